// Round 1
// 531.105 us; speedup vs baseline: 1.1421x; 1.1421x over previous
//
#include <hip/hip_runtime.h>
#include <hip/hip_bf16.h>
#include <cstdint>
#include <cstddef>

// out[8192,4096] = x @ W^T + bias + 2*((x@A^T)@B^T)
// Fold: W' = W + 2*B@A (rank-16), then ONE bf16 MFMA GEMM: out = x @ W'^T + bias.
// R3: GEMM rewritten as 256x256-tile ring-4 deep pipeline (T2+T3+T4+T5):
//     - 4 LDS buffers (128 KB), stage tile p+3 while computing tile p
//     - counted s_waitcnt vmcnt(8) across raw s_barrier (never drain in main loop)
//     - XOR chunk swizzle (pre-swizzled global src + swizzled ds_read) -> 0 bank conflicts
//     - inline-asm ds_read_b128 + lgkmcnt + sched_barrier(0)  (rule 18)
//     - s_setprio(1) around MFMA cluster

#define IN_F   4096
#define OUT_F  4096
#define MROWS  8192   // 4*2048
#define RLORA  16
#define LORA_SCALE 2.0f

#define CAST_BLOCKS 32768   // MROWS*IN_F / (4*256)
#define FOLD_BLOCKS 4096    // OUT_F

// GEMM geometry
#define BM   256
#define BN   256
#define BKT  32               // K per pipeline sub-tile
#define NT   (IN_F / BKT)     // 128 phases

typedef __bf16 bf16x8 __attribute__((ext_vector_type(8)));
typedef float  f32x4  __attribute__((ext_vector_type(4)));
typedef int    i32x4  __attribute__((ext_vector_type(4)));

__device__ __forceinline__ unsigned short f2bf_rne(float f) {
    union { float f; unsigned u; } v; v.f = f;
    unsigned u = v.u;
    return (unsigned short)((u + 0x7FFFu + ((u >> 16) & 1u)) >> 16);
}

__device__ __forceinline__ void gl_lds16(const unsigned short* g, unsigned short* l) {
    __builtin_amdgcn_global_load_lds(
        (const __attribute__((address_space(1))) unsigned int*)g,
        (__attribute__((address_space(3))) unsigned int*)l,
        16, 0, 0);
}

// ---- prep: blocks [0,32768) cast x fp32->bf16; [32768,36864) fold W' -------

__global__ void prep_kernel(const float* __restrict__ x,
                            const float* __restrict__ W,
                            const float* __restrict__ A,
                            const float* __restrict__ B,
                            unsigned short* __restrict__ xb,
                            unsigned short* __restrict__ wb) {
    __shared__ float sB[RLORA];
    const int bid = blockIdx.x;
    if (bid < CAST_BLOCKS) {
        int i = bid * blockDim.x + threadIdx.x;       // one float4 per thread
        float4 v = ((const float4*)x)[i];
        ushort4 o;
        o.x = f2bf_rne(v.x); o.y = f2bf_rne(v.y);
        o.z = f2bf_rne(v.z); o.w = f2bf_rne(v.w);
        ((ushort4*)xb)[i] = o;
    } else {
        const int o = bid - CAST_BLOCKS;              // output row
        if (threadIdx.x < RLORA) sB[threadIdx.x] = B[o * RLORA + threadIdx.x];
        __syncthreads();
        const float4* W4  = (const float4*)(W + (size_t)o * IN_F);
        ushort4*      Wp4 = (ushort4*)(wb + (size_t)o * IN_F);
        for (int i4 = threadIdx.x; i4 < IN_F / 4; i4 += blockDim.x) {
            float4 w = W4[i4];
            float ax = 0.f, ay = 0.f, az = 0.f, aw = 0.f;
            #pragma unroll
            for (int r = 0; r < RLORA; ++r) {
                float4 a = ((const float4*)(A + (size_t)r * IN_F))[i4];
                float s = sB[r];
                ax += s * a.x; ay += s * a.y; az += s * a.z; aw += s * a.w;
            }
            w.x += LORA_SCALE * ax; w.y += LORA_SCALE * ay;
            w.z += LORA_SCALE * az; w.w += LORA_SCALE * aw;
            ushort4 ov;
            ov.x = f2bf_rne(w.x); ov.y = f2bf_rne(w.y);
            ov.z = f2bf_rne(w.z); ov.w = f2bf_rne(w.w);
            Wp4[i4] = ov;
        }
    }
}

// ---- GEMM: C[M,N] = Xb @ Wb^T + bias  (ring-4 pipelined 256x256 tile) ------
//
// LDS chunk swizzle (chunk = 16 B = 8 bf16):
//   LDS byte(row, kc) = row*64 + ((kc ^ ((row>>1)&3))<<4)
//   -> every aligned 8-lane group of a fragment ds_read_b128 covers all 32 banks.
// global_load_lds writes LINEAR chunks (rule #21); the stage source address is
// pre-swizzled: LDS chunk q holds global chunk (row=q>>2, kc=(q&3)^((row>>1)&3)).
//
// Pipeline invariant: tile p lives in buf[p&3]; phase p stages tile p+3 into
// buf[(p+3)&3] == buf[(p-1)&3] (last read at phase p-1, behind the barrier).
// End-of-phase s_waitcnt vmcnt(8) confirms tile p+1 staged (4 loads/thread per
// tile, in-order retirement), then s_barrier -> all waves' portions visible.

__global__ __launch_bounds__(512, 2)
void gemm_bt_bias(const unsigned short* __restrict__ Xb,
                  const unsigned short* __restrict__ Wb,
                  const float* __restrict__ bias,
                  float* __restrict__ out) {
    __shared__ __align__(16) unsigned short smem[4 * 16384];  // 4 bufs x (A 16KB + B 16KB)

    const int tid  = threadIdx.x;
    const int wave = tid >> 6;      // 0..7
    const int lane = tid & 63;
    const int quad = lane >> 4;     // 0..3
    const int r16  = lane & 15;
    const int wm   = wave >> 2;     // 0..1 (M half)
    const int wn   = wave & 3;      // 0..3 (N quarter)

    // XCD swizzle: 512 wgs / 8 XCDs = 64 per XCD. XCD c owns N-tiles {2c,2c+1}:
    // W panel 2*256*4096*2B = 4 MB = its whole L2, resident all kernel.
    const int bid = blockIdx.x;
    const int xcd = bid & 7;
    const int t   = bid >> 3;                    // 0..63
    const int n0  = (xcd * 2 + (t & 1)) * BN;    // N-tile
    const int m0  = (t >> 1) * BM;               // M-tile (consecutive t share X panel)

    // ---- staging geometry (per thread: 2 A-chunks + 2 B-chunks per tile) ----
    const int qA0 = wave * 128 + lane;           // LDS chunk index, instr 0
    const int qA1 = qA0 + 64;                    // instr 1
    const int rA0 = qA0 >> 2, kA0 = (qA0 & 3) ^ ((rA0 >> 1) & 3);
    const int rA1 = qA1 >> 2, kA1 = (qA1 & 3) ^ ((rA1 >> 1) & 3);

    const unsigned short* gA0 = Xb + (size_t)(m0 + rA0) * IN_F + kA0 * 8;
    const unsigned short* gA1 = Xb + (size_t)(m0 + rA1) * IN_F + kA1 * 8;
    const unsigned short* gB0 = Wb + (size_t)(n0 + rA0) * IN_F + kA0 * 8;
    const unsigned short* gB1 = Wb + (size_t)(n0 + rA1) * IN_F + kA1 * 8;

    const unsigned dA0 = wave * 1024;            // ushort offsets inside a buffer
    const unsigned dA1 = dA0 + 512;
    const unsigned dB0 = 8192 + wave * 1024;     // B region at +16 KB
    const unsigned dB1 = dB0 + 512;

    // ---- fragment read addresses (bytes, swizzled) --------------------------
    const unsigned slot  = (unsigned)(quad ^ ((r16 >> 1) & 3));
    const unsigned aoff  = (unsigned)((wm * 128 + r16) * 64) + slot * 16;
    const unsigned boff  = 16384u + (unsigned)((wn * 64 + r16) * 64) + slot * 16;
    const unsigned sbase = (unsigned)(size_t)
        ((__attribute__((address_space(3))) unsigned short*)smem);

    f32x4 acc[8][4] = {};

    // ---- prologue: stage tiles 0,1,2 ---------------------------------------
    #pragma unroll
    for (int s = 0; s < 3; ++s) {
        unsigned short* Lb = smem + (s << 14);
        gl_lds16(gA0, Lb + dA0); gl_lds16(gA1, Lb + dA1);
        gl_lds16(gB0, Lb + dB0); gl_lds16(gB1, Lb + dB1);
        gA0 += BKT; gA1 += BKT; gB0 += BKT; gB1 += BKT;
    }
    asm volatile("s_waitcnt vmcnt(8)" ::: "memory");   // tile 0 confirmed
    __builtin_amdgcn_s_barrier();

    // ---- main loop ----------------------------------------------------------
    for (int p = 0; p < NT; ++p) {
        if (p + 3 < NT) {                        // stage tile p+3
            unsigned short* Lb = smem + (((p + 3) & 3) << 14);
            gl_lds16(gA0, Lb + dA0); gl_lds16(gA1, Lb + dA1);
            gl_lds16(gB0, Lb + dB0); gl_lds16(gB1, Lb + dB1);
            gA0 += BKT; gA1 += BKT; gB0 += BKT; gB1 += BKT;
        }

        const unsigned bufb = sbase + ((unsigned)(p & 3) << 15);
        const unsigned ab = bufb + aoff;
        const unsigned bb = bufb + boff;

        i32x4 aR[8]; i32x4 bR[4];
        asm volatile("ds_read_b128 %0, %1"             : "=v"(bR[0]) : "v"(bb));
        asm volatile("ds_read_b128 %0, %1 offset:1024" : "=v"(bR[1]) : "v"(bb));
        asm volatile("ds_read_b128 %0, %1 offset:2048" : "=v"(bR[2]) : "v"(bb));
        asm volatile("ds_read_b128 %0, %1 offset:3072" : "=v"(bR[3]) : "v"(bb));
        asm volatile("ds_read_b128 %0, %1"             : "=v"(aR[0]) : "v"(ab));
        asm volatile("ds_read_b128 %0, %1 offset:1024" : "=v"(aR[1]) : "v"(ab));
        asm volatile("ds_read_b128 %0, %1 offset:2048" : "=v"(aR[2]) : "v"(ab));
        asm volatile("ds_read_b128 %0, %1 offset:3072" : "=v"(aR[3]) : "v"(ab));
        asm volatile("ds_read_b128 %0, %1 offset:4096" : "=v"(aR[4]) : "v"(ab));
        asm volatile("ds_read_b128 %0, %1 offset:5120" : "=v"(aR[5]) : "v"(ab));
        asm volatile("ds_read_b128 %0, %1 offset:6144" : "=v"(aR[6]) : "v"(ab));
        asm volatile("ds_read_b128 %0, %1 offset:7168" : "=v"(aR[7]) : "v"(ab));

        // cluster 1 needs the first 8 reads (B0-3, A0-3); allow A4-7 in flight
        asm volatile("s_waitcnt lgkmcnt(4)" ::: "memory");
        __builtin_amdgcn_sched_barrier(0);
        __builtin_amdgcn_s_setprio(1);
        #pragma unroll
        for (int mi = 0; mi < 4; ++mi) {
            const bf16x8 a = __builtin_bit_cast(bf16x8, aR[mi]);
            #pragma unroll
            for (int nj = 0; nj < 4; ++nj)
                acc[mi][nj] = __builtin_amdgcn_mfma_f32_16x16x32_bf16(
                    a, __builtin_bit_cast(bf16x8, bR[nj]), acc[mi][nj], 0, 0, 0);
        }
        asm volatile("s_waitcnt lgkmcnt(0)" ::: "memory");
        __builtin_amdgcn_sched_barrier(0);
        #pragma unroll
        for (int mi = 4; mi < 8; ++mi) {
            const bf16x8 a = __builtin_bit_cast(bf16x8, aR[mi]);
            #pragma unroll
            for (int nj = 0; nj < 4; ++nj)
                acc[mi][nj] = __builtin_amdgcn_mfma_f32_16x16x32_bf16(
                    a, __builtin_bit_cast(bf16x8, bR[nj]), acc[mi][nj], 0, 0, 0);
        }
        __builtin_amdgcn_sched_barrier(0);
        __builtin_amdgcn_s_setprio(0);

        // confirm tile p+1 before next phase reads it (in-order retirement):
        //   steady: 2 tiles (p+2,p+3) allowed outstanding = 8 loads
        //   p==NT-3: only tile NT-1 outstanding = 4 loads; after that: drain
        if (p + 3 < NT)       { asm volatile("s_waitcnt vmcnt(8)" ::: "memory"); }
        else if (p + 3 == NT) { asm volatile("s_waitcnt vmcnt(4)" ::: "memory"); }
        else                  { asm volatile("s_waitcnt vmcnt(0)" ::: "memory"); }
        __builtin_amdgcn_s_barrier();
    }

    // ---- epilogue: C = acc + bias ------------------------------------------
    float bv[4];
    #pragma unroll
    for (int nj = 0; nj < 4; ++nj)
        bv[nj] = bias[n0 + wn * 64 + nj * 16 + r16];

    #pragma unroll
    for (int mi = 0; mi < 8; ++mi) {
        #pragma unroll
        for (int i = 0; i < 4; ++i) {
            const int mg = m0 + wm * 128 + mi * 16 + quad * 4 + i;
            float* orow = out + (size_t)mg * OUT_F + (n0 + wn * 64 + r16);
            #pragma unroll
            for (int nj = 0; nj < 4; ++nj)
                orow[nj * 16] = acc[mi][nj][i] + bv[nj];
        }
    }
}

// ---- launch ----------------------------------------------------------------

extern "C" void kernel_launch(void* const* d_in, const int* in_sizes, int n_in,
                              void* d_out, int out_size, void* d_ws, size_t ws_size,
                              hipStream_t stream) {
    const float* x    = (const float*)d_in[0];
    const float* W    = (const float*)d_in[1];
    const float* bias = (const float*)d_in[2];
    const float* A    = (const float*)d_in[3];
    const float* B    = (const float*)d_in[4];
    float* out = (float*)d_out;

    unsigned short* xb = (unsigned short*)d_ws;              // 64 MB bf16 x
    unsigned short* wb = xb + (size_t)MROWS * IN_F;          // 32 MB bf16 W'

    prep_kernel<<<CAST_BLOCKS + FOLD_BLOCKS, 256, 0, stream>>>(x, W, A, B, xb, wb);
    gemm_bt_bias<<<(MROWS / BM) * (OUT_F / BN), 512, 0, stream>>>(xb, wb, bias, out);
}